// Round 8
// baseline (187.410 us; speedup 1.0000x reference)
//
#include <hip/hip_runtime.h>
#include <hip/hip_bf16.h>
#include <cstddef>

// Dims fixed by reference: B=2, S=2048, H=1024, NH=4, DH=256
constexpr int Bx = 2, Sx = 2048, Hx = 1024, NHx = 4, DHx = 256;
constexpr float RSQ = 0.0625f;   // 1/sqrt(256)

typedef __attribute__((ext_vector_type(8))) short    bf16x8;
typedef __attribute__((ext_vector_type(4))) float    f32x4;
typedef __attribute__((ext_vector_type(4))) unsigned u32x4;

__device__ __forceinline__ float logsigf(float x) {
  return (x >= 0.0f) ? -log1pf(expf(-x)) : x - log1pf(expf(x));
}
__device__ __forceinline__ unsigned short f2bf(float x) {  // RNE f32->bf16
  unsigned u = __builtin_bit_cast(unsigned, x);
  u = (u + 0x7fffu + ((u >> 16) & 1u)) >> 16;
  return (unsigned short)u;
}
__device__ __forceinline__ unsigned pk2bf(float a, float b) {
  return (unsigned)f2bf(a) | ((unsigned)f2bf(b) << 16);
}

// ---------- K1: gates (ig/fg) + bf16 side-copies of Q,K ---------------------
// 16 rows per block (512 thr = 8 waves, 2 rows/wave) to amortize W reads.
__global__ __launch_bounds__(512)
void gates_kernel(const float* __restrict__ q, const float* __restrict__ k,
                  const float* __restrict__ v,
                  const float* __restrict__ wi, const float* __restrict__ bi,
                  const float* __restrict__ wf, const float* __restrict__ bf,
                  float* __restrict__ ig, float* __restrict__ fg,
                  unsigned short* __restrict__ Qb, unsigned short* __restrict__ Kb)
{
  const int w = threadIdx.x >> 6, l = threadIdx.x & 63;
  const int bs0 = blockIdx.x * 16;
  const int bsr0 = bs0 + w * 2, bsr1 = bsr0 + 1;
  float p[2][8];
#pragma unroll
  for (int rr = 0; rr < 2; ++rr)
#pragma unroll
    for (int g2 = 0; g2 < 8; ++g2) p[rr][g2] = 0.f;

#pragma unroll
  for (int chunk = 0; chunk < 12; ++chunk) {
    const int idx = l * 4 + chunk * 256;     // 0..3071
    const float* src; int off;
    if (idx < 1024)       { src = q; off = idx; }
    else if (idx < 2048)  { src = k; off = idx - 1024; }
    else                  { src = v; off = idx - 2048; }
    float4 g0 = *(const float4*)(src + (size_t)bsr0 * Hx + off);
    float4 g1 = *(const float4*)(src + (size_t)bsr1 * Hx + off);
#pragma unroll
    for (int h = 0; h < 4; ++h) {
      float4 wiv = *(const float4*)(wi + h * 3 * Hx + idx);
      float4 wfv = *(const float4*)(wf + h * 3 * Hx + idx);
      p[0][h]     += g0.x*wiv.x + g0.y*wiv.y + g0.z*wiv.z + g0.w*wiv.w;
      p[1][h]     += g1.x*wiv.x + g1.y*wiv.y + g1.z*wiv.z + g1.w*wiv.w;
      p[0][4 + h] += g0.x*wfv.x + g0.y*wfv.y + g0.z*wfv.z + g0.w*wfv.w;
      p[1][4 + h] += g1.x*wfv.x + g1.y*wfv.y + g1.z*wfv.z + g1.w*wfv.w;
    }
    if (idx < 2048) {
      unsigned short* dst = (idx < 1024) ? Qb : Kb;
      const int hh = off >> 8, d = off & 255;
      const int b0 = bsr0 >> 11, s0p = bsr0 & 2047;
      const int b1 = bsr1 >> 11, s1p = bsr1 & 2047;
      ushort4 o0; o0.x=f2bf(g0.x); o0.y=f2bf(g0.y); o0.z=f2bf(g0.z); o0.w=f2bf(g0.w);
      ushort4 o1; o1.x=f2bf(g1.x); o1.y=f2bf(g1.y); o1.z=f2bf(g1.z); o1.w=f2bf(g1.w);
      *(ushort4*)(dst + ((size_t)(b0 * NHx + hh) * Sx + s0p) * DHx + d) = o0;
      *(ushort4*)(dst + ((size_t)(b1 * NHx + hh) * Sx + s1p) * DHx + d) = o1;
    }
  }
#pragma unroll
  for (int rr = 0; rr < 2; ++rr)
#pragma unroll
    for (int g2 = 0; g2 < 8; ++g2) {
      float x = p[rr][g2];
      x += __shfl_xor(x, 1);  x += __shfl_xor(x, 2);  x += __shfl_xor(x, 4);
      x += __shfl_xor(x, 8);  x += __shfl_xor(x, 16); x += __shfl_xor(x, 32);
      p[rr][g2] = x;
    }
  if (l == 0) {
#pragma unroll
    for (int rr = 0; rr < 2; ++rr) {
      const int bs = bs0 + w * 2 + rr;
      const int b = bs >> 11, spos = bs & 2047;
#pragma unroll
      for (int h = 0; h < 4; ++h) {
        ig[(size_t)(b * NHx + h) * Sx + spos] = p[rr][h] + bi[h];
        fg[(size_t)(b * NHx + h) * Sx + spos] = p[rr][4 + h] + bf[h];
      }
    }
  }
}

// ---------- K2: per-(b,h) scan: a[], M[], exp(-m)[] -------------------------
__global__ __launch_bounds__(256)
void scan_kernel(const float* __restrict__ ig, const float* __restrict__ fg,
                 float* __restrict__ av, float* __restrict__ Mv,
                 float* __restrict__ nfv)
{
  const int bh = blockIdx.x;
  const int t  = threadIdx.x;
  const size_t base = (size_t)bh * Sx;
  const int s0 = t * 8;
  float4 f0 = *(const float4*)(fg + base + s0);
  float4 f1 = *(const float4*)(fg + base + s0 + 4);
  float4 g0 = *(const float4*)(ig + base + s0);
  float4 g1 = *(const float4*)(ig + base + s0 + 4);
  float xf[8] = {f0.x,f0.y,f0.z,f0.w,f1.x,f1.y,f1.z,f1.w};
  float xi[8] = {g0.x,g0.y,g0.z,g0.w,g1.x,g1.y,g1.z,g1.w};
  float ps[8];
  float run = 0.0f;
#pragma unroll
  for (int i = 0; i < 8; ++i) { run += logsigf(xf[i]); ps[i] = run; }
  __shared__ float ssum[256];
  __shared__ float smax[256];
  ssum[t] = run;
  __syncthreads();
  for (int st = 1; st < 256; st <<= 1) {
    float addv = (t >= st) ? ssum[t - st] : 0.0f;
    __syncthreads();
    ssum[t] += addv;
    __syncthreads();
  }
  const float exs = (t > 0) ? ssum[t - 1] : 0.0f;
  float a[8], pm[8];
  float rm = -INFINITY;
#pragma unroll
  for (int i = 0; i < 8; ++i) {
    a[i] = xi[i] - (exs + ps[i]);
    rm = fmaxf(rm, a[i]);
    pm[i] = rm;
  }
  smax[t] = rm;
  __syncthreads();
  for (int st = 1; st < 256; st <<= 1) {
    float mv = (t >= st) ? smax[t - st] : -INFINITY;
    __syncthreads();
    smax[t] = fmaxf(smax[t], mv);
    __syncthreads();
  }
  const float exm = (t > 0) ? smax[t - 1] : -INFINITY;
#pragma unroll
  for (int i = 0; i < 8; ++i) {
    const float M = fmaxf(exm, pm[i]);
    const float F = exs + ps[i];
    av[base + s0 + i]  = a[i];
    Mv[base + s0 + i]  = M;
    nfv[base + s0 + i] = expf(-(F + M));
  }
}

// ---------- K3: V -> bf16 transposed global Vt[bh][d][s] --------------------
__global__ __launch_bounds__(256)
void vtrans_kernel(const float* __restrict__ v, unsigned short* __restrict__ vt)
{
  __shared__ float tile[64][68];
  const int st0 = blockIdx.x * 64, dt0 = blockIdx.y * 64;
  const int bh = blockIdx.z, b = bh >> 2, h = bh & 3;
  const int t = threadIdx.x;
#pragma unroll
  for (int i = 0; i < 4; ++i) {
    int u = t + 256 * i;
    int r = u >> 4, c4 = (u & 15) * 4;
    const float* p = v + ((size_t)(b * Sx) + st0 + r) * Hx + h * DHx + dt0 + c4;
    float4 vv = *(const float4*)p;
    tile[r][c4] = vv.x; tile[r][c4+1] = vv.y; tile[r][c4+2] = vv.z; tile[r][c4+3] = vv.w;
  }
  __syncthreads();
#pragma unroll
  for (int i = 0; i < 4; ++i) {
    int u = t + 256 * i;
    int dr = u >> 4, c4 = (u & 15) * 4;
    ushort4 o;
    o.x = f2bf(tile[c4+0][dr]); o.y = f2bf(tile[c4+1][dr]);
    o.z = f2bf(tile[c4+2][dr]); o.w = f2bf(tile[c4+3][dr]);
    *(ushort4*)(vt + ((size_t)bh * DHx + dt0 + dr) * Sx + st0 + c4) = o;
  }
}

// ---------- K4: flash mLSTM on MFMA, barrier-free 1-wave blocks --------------
// 64 thr = 1 wave per block; wave owns 16 q-rows; loops BK=32 key tiles.
// Swapped QK^T: st = mfma(A=K16, B=Q16) -> lane ll holds P[q=ll][keys lg*4+r].
// In-register repack (cvt_pk + shfl_xor 16/32) -> P^T B-frag; PV: A=V^T frags
// direct from L2. No LDS, no __syncthreads anywhere in the loop.
__global__ __launch_bounds__(64, 2)
void mlstm_mfma(const unsigned short* __restrict__ Qb,
                const unsigned short* __restrict__ Kb,
                const unsigned short* __restrict__ Vt,
                const float* __restrict__ av, const float* __restrict__ Mv,
                const float* __restrict__ nfv, const float* __restrict__ lnw,
                float* __restrict__ out)
{
  const int bh = blockIdx.x, b = bh >> 2, h = bh & 3;
  const int ti = (int)gridDim.y - 1 - (int)blockIdx.y;   // big tiles first
  const int i0 = ti * 16;
  const int l = threadIdx.x;
  const int lg = l >> 4, ll = l & 15;
  const size_t bhS = (size_t)bh * Sx;
  const int qrow = i0 + ll;

  // Q B-frags: q=ll, d = d8*32 + lg*8
  bf16x8 qf[8];
  {
    const unsigned short* qp = Qb + (bhS + qrow) * DHx + lg * 8;
#pragma unroll
    for (int d8 = 0; d8 < 8; ++d8) qf[d8] = *(const bf16x8*)(qp + d8 * 32);
  }
  const float Mq = Mv[bhS + qrow];

  f32x4 acc[16];
#pragma unroll
  for (int jt = 0; jt < 16; ++jt) acc[jt] = f32x4{0, 0, 0, 0};
  float rsum = 0.f;

  const int nt = (i0 + 47) >> 5;     // ceil((i0+16)/32)
  const unsigned short* kb0 = Kb + (bhS + ll) * DHx + lg * 8;
  const unsigned short* vb0 = Vt + ((size_t)bh * DHx + ll) * Sx + lg * 8;

  // prefetch V A-frags (dsub 0..7) for tile 0
  bf16x8 vfA[8], vfB[8];
#pragma unroll
  for (int ds = 0; ds < 8; ++ds)
    vfA[ds] = *(const bf16x8*)(vb0 + (size_t)(ds * 16) * Sx);

  for (int tj = 0; tj < nt; ++tj) {
    const int j0 = tj * 32;
    // issue V frags dsub 8..15 for this tile (land during QK)
#pragma unroll
    for (int ds = 0; ds < 8; ++ds)
      vfB[ds] = *(const bf16x8*)(vb0 + (size_t)((ds + 8) * 16) * Sx + j0);
    const f32x4 a4_0 = *(const f32x4*)(av + bhS + j0 + lg * 4);
    const f32x4 a4_1 = *(const f32x4*)(av + bhS + j0 + 16 + lg * 4);

    // ---- QK: two 16-key subtiles, K frags direct from L2 ----
    f32x4 st0 = {0,0,0,0}, st1 = {0,0,0,0};
    {
      const unsigned short* kp = kb0 + (size_t)j0 * DHx;
      bf16x8 kf[8];
#pragma unroll
      for (int d8 = 0; d8 < 8; ++d8) kf[d8] = *(const bf16x8*)(kp + d8 * 32);
#pragma unroll
      for (int d8 = 0; d8 < 8; ++d8)
        st0 = __builtin_amdgcn_mfma_f32_16x16x32_bf16(kf[d8], qf[d8], st0, 0, 0, 0);
#pragma unroll
      for (int d8 = 0; d8 < 8; ++d8) kf[d8] = *(const bf16x8*)(kp + 16 * DHx + d8 * 32);
#pragma unroll
      for (int d8 = 0; d8 < 8; ++d8)
        st1 = __builtin_amdgcn_mfma_f32_16x16x32_bf16(kf[d8], qf[d8], st1, 0, 0, 0);
    }

    // ---- transform: mask + decay + rsum; pack to bf16; lane redistribution --
    unsigned x0[4], x1[4];
#pragma unroll
    for (int kt = 0; kt < 2; ++kt) {
      const f32x4 s = kt ? st1 : st0;
      const f32x4 a = kt ? a4_1 : a4_0;
      const int kb = j0 + kt * 16 + 4 * lg;
      float p0 = (kb + 0 <= qrow) ? s[0] * (RSQ * __expf(a[0] - Mq)) : 0.f;
      float p1 = (kb + 1 <= qrow) ? s[1] * (RSQ * __expf(a[1] - Mq)) : 0.f;
      float p2 = (kb + 2 <= qrow) ? s[2] * (RSQ * __expf(a[2] - Mq)) : 0.f;
      float p3 = (kb + 3 <= qrow) ? s[3] * (RSQ * __expf(a[3] - Mq)) : 0.f;
      rsum += (p0 + p1) + (p2 + p3);
      unsigned lo = pk2bf(p0, p1), hi = pk2bf(p2, p3);
      unsigned plo = __shfl_xor(lo, 16), phi = __shfl_xor(hi, 16);
      bool ge = ((lg & 1) == 0);
      unsigned* x = kt ? x1 : x0;
      x[0] = ge ? lo : plo;  x[1] = ge ? hi : phi;
      x[2] = ge ? plo : lo;  x[3] = ge ? phi : hi;
    }
    unsigned pw0, pw1, pw2, pw3;
#pragma unroll
    for (int j = 0; j < 4; ++j) {
      unsigned yA = __shfl_xor(x0[j], 32);
      unsigned yB = __shfl_xor(x1[j], 32);
      unsigned r = (lg == 0) ? x0[j] : (lg == 1) ? yA : (lg == 2) ? yB : x1[j];
      if (j == 0) pw0 = r; else if (j == 1) pw1 = r; else if (j == 2) pw2 = r; else pw3 = r;
    }
    u32x4 w4 = {pw0, pw1, pw2, pw3};
    bf16x8 pb = __builtin_bit_cast(bf16x8, w4);

    // ---- PV dsub 0..7 (vfA prefetched last iter) ----
#pragma unroll
    for (int ds = 0; ds < 8; ++ds)
      acc[ds] = __builtin_amdgcn_mfma_f32_16x16x32_bf16(vfA[ds], pb, acc[ds], 0, 0, 0);
    // ---- prefetch vfA for next tile (hidden under PV-B + next QK) ----
    const int jn = (tj + 1 < nt) ? (tj + 1) * 32 : j0;
#pragma unroll
    for (int ds = 0; ds < 8; ++ds)
      vfA[ds] = *(const bf16x8*)(vb0 + (size_t)(ds * 16) * Sx + jn);
    // ---- PV dsub 8..15 ----
#pragma unroll
    for (int ds = 0; ds < 8; ++ds)
      acc[8 + ds] = __builtin_amdgcn_mfma_f32_16x16x32_bf16(vfB[ds], pb, acc[8 + ds], 0, 0, 0);
  }

  // ---- epilogue: all reductions via shfl (lanes lg differ, ll fixed) ----
  float rs = rsum;
  rs += __shfl_xor(rs, 16); rs += __shfl_xor(rs, 32);
  float s1 = 0.f, s2 = 0.f;
#pragma unroll
  for (int jt = 0; jt < 16; ++jt) {
#pragma unroll
    for (int r = 0; r < 4; ++r) {
      const float x = acc[jt][r];
      s1 += x; s2 += x * x;
    }
  }
  s1 += __shfl_xor(s1, 16); s1 += __shfl_xor(s1, 32);
  s2 += __shfl_xor(s2, 16); s2 += __shfl_xor(s2, 32);
  const float nf = nfv[bhS + qrow];
  const float inv = 1.f / (fmaxf(fabsf(rs), nf) + 1e-6f);
  const float mean = s1 * inv * (1.f / 256.f);
  const float ex2  = s2 * inv * inv * (1.f / 256.f);
  const float var  = ex2 - mean * mean;
  const float rstd = rsqrtf(var + 1e-5f);
  float* op = out + ((size_t)b * Sx + qrow) * Hx + h * DHx;
#pragma unroll
  for (int jt = 0; jt < 16; ++jt) {
    const int dbase = jt * 16 + 4 * lg;
    f32x4 lw = *(const f32x4*)(lnw + h * DHx + dbase);
    float4 o;
    o.x = (acc[jt][0] * inv - mean) * rstd * (1.f + lw[0]);
    o.y = (acc[jt][1] * inv - mean) * rstd * (1.f + lw[1]);
    o.z = (acc[jt][2] * inv - mean) * rstd * (1.f + lw[2]);
    o.w = (acc[jt][3] * inv - mean) * rstd * (1.f + lw[3]);
    *(float4*)(op + dbase) = o;
  }
}

extern "C" void kernel_launch(void* const* d_in, const int* in_sizes, int n_in,
                              void* d_out, int out_size, void* d_ws, size_t ws_size,
                              hipStream_t stream) {
  const float* q   = (const float*)d_in[0];
  const float* k   = (const float*)d_in[1];
  const float* v   = (const float*)d_in[2];
  const float* wi  = (const float*)d_in[3];
  const float* bi  = (const float*)d_in[4];
  const float* wf  = (const float*)d_in[5];
  const float* bf  = (const float*)d_in[6];
  const float* lnw = (const float*)d_in[7];
  float* out = (float*)d_out;
  float* ws  = (float*)d_ws;

  const int G = Bx * NHx * Sx;         // 16384
  float* ig  = ws;
  float* fg  = ws + (size_t)G;
  float* av  = ws + (size_t)2 * G;
  float* Mv  = ws + (size_t)3 * G;
  float* nfv = ws + (size_t)4 * G;
  unsigned short* Qb = (unsigned short*)(ws + (size_t)5 * G);
  unsigned short* Kb = Qb + (size_t)Bx * Sx * Hx;   // 4,194,304 elems
  unsigned short* Vt = Kb + (size_t)Bx * Sx * Hx;
  // total ws use: ~24.3 MB

  gates_kernel<<<Bx * Sx / 16, 512, 0, stream>>>(q, k, v, wi, bi, wf, bf, ig, fg, Qb, Kb);
  scan_kernel<<<Bx * NHx, 256, 0, stream>>>(ig, fg, av, Mv, nfv);
  dim3 gT(Sx / 64, DHx / 64, Bx * NHx);
  vtrans_kernel<<<gT, 256, 0, stream>>>(v, Vt);
  dim3 g4(Bx * NHx, Sx / 16);          // x = bh (XCD pinned), y = q-tile
  mlstm_mfma<<<g4, 64, 0, stream>>>(Qb, Kb, Vt, av, Mv, nfv, lnw, out);
}